// Round 1
// 782.614 us; speedup vs baseline: 1.0356x; 1.0356x over previous
//
#include <hip/hip_runtime.h>
#include <math.h>

#define Bb 64
#define Tt 512
#define Dd 1536
#define Hh 30
#define NC 128            // packed GX cols: gate layout unchanged (scan_k untouched)
#define Mm (Bb*Tt)        // 32768 rows
#define KSTEPS 48         // 1536 / 32

typedef unsigned short u16;
typedef __attribute__((ext_vector_type(8))) short short8v;  // 8 bf16 = 4 VGPRs
typedef __attribute__((ext_vector_type(4))) float f32x4;

__device__ __forceinline__ float rcpf_(float x) { return __builtin_amdgcn_rcpf(x); }
__device__ __forceinline__ float sigmoidf_(float x) {
    return rcpf_(1.f + __expf(-x));
}
__device__ __forceinline__ float tanhf_fast(float x) {
    float e = __expf(2.f * x);
    return fmaf(-2.f, rcpf_(e + 1.f), 1.f);
}
__device__ __forceinline__ float softplus_(float x) {
    return fmaxf(x, 0.f) + __logf(1.f + __expf(-fabsf(x)));
}
__device__ __forceinline__ float rl_f(float v, int lane) {
    return __uint_as_float(__builtin_amdgcn_readlane(__float_as_uint(v), lane));
}

__device__ __forceinline__ f32x4 mm_bf16(short8v a, short8v b, f32x4 c) {
    return __builtin_amdgcn_mfma_f32_16x16x32_bf16(a, b, c, 0, 0, 0);
}

union U4S8 { unsigned int u[4]; short8v s; };

// exact hi/lo split: x = hi + lo with hi = trunc-bf16(x) (x - hi exact in fp32),
// lo truncated to bf16 (residual ~2^-16 |x| -> dropped Al*Bl term ~2^-16 rel).
__device__ __forceinline__ void cvt_split(const float4 a, const float4 b,
                                          short8v& hi, short8v& lo) {
    float x[8] = {a.x, a.y, a.z, a.w, b.x, b.y, b.z, b.w};
    U4S8 H, L;
#pragma unroll
    for (int i = 0; i < 4; i++) {
        unsigned int u0 = __float_as_uint(x[2 * i]);
        unsigned int u1 = __float_as_uint(x[2 * i + 1]);
        unsigned int h0 = u0 & 0xffff0000u;
        unsigned int h1 = u1 & 0xffff0000u;
        H.u[i] = (u0 >> 16) | h1;
        float l0 = x[2 * i]     - __uint_as_float(h0);
        float l1 = x[2 * i + 1] - __uint_as_float(h1);
        L.u[i] = (__float_as_uint(l0) >> 16) | (__float_as_uint(l1) & 0xffff0000u);
    }
    hi = H.s;
    lo = L.s;
}

// ---------------- pack 1: W -> bf16 hi/lo, col-major Wb*[c][k] ----------------
// col-major (k contiguous per col) == B-fragment order for mfma 16x16x32 bf16.
__global__ __launch_bounds__(256) void pack_w(const float* __restrict__ Wih,
                                              const float* __restrict__ Wa,
                                              const float* __restrict__ Wb,
                                              u16* __restrict__ Wbh,
                                              u16* __restrict__ Wbl) {
    const int k = blockIdx.x * 256 + threadIdx.x;  // 0..1535
    const int c = blockIdx.y;                      // 0..127
    float v = 0.f;
    if (c < 120)       v = Wih[c * (Dd + 1) + k];
    else if (c == 120) v = Wa[k];
    else if (c == 121) v = Wb[k];
    unsigned int u = __float_as_uint(v);
    unsigned int h = u & 0xffff0000u;
    float lo = v - __uint_as_float(h);
    Wbh[(size_t)c * Dd + k] = (u16)(u >> 16);
    Wbl[(size_t)c * Dd + k] = (u16)(__float_as_uint(lo) >> 16);
}

// ---------------- pack 2: scan weight tables WAp/WBp[64][32] (UNCHANGED) ------
__global__ __launch_bounds__(256) void pack_s(const float* __restrict__ Wih,
                                              const float* __restrict__ Whh,
                                              const float* __restrict__ Wa,
                                              const float* __restrict__ Wb,
                                              float* __restrict__ WAp,
                                              float* __restrict__ WBp) {
    int t = threadIdx.x;
    for (int idx = t; idx < 64 * 32; idx += 256) {
        int l = idx >> 5, k = idx & 31;
        float va = 0.f, vb = 0.f;
        if (k < 30) {
            if (l < 30)                 { va = Whh[l * Hh + k];        vb = Whh[(30 + l) * Hh + k]; }
            else if (l == 30)           { va = Wa[Dd + k]; }
            else if (l == 31)           { va = Wb[Dd + k]; }
            else if (l < 62)            { va = Whh[(l + 28) * Hh + k]; vb = Whh[(l + 58) * Hh + k]; }
        } else if (k == 30) {
            if (l < 30)                 { va = Wih[l * (Dd + 1) + Dd];        vb = Wih[(30 + l) * (Dd + 1) + Dd]; }
            else if (l >= 32 && l < 62) { va = Wih[(l + 28) * (Dd + 1) + Dd]; vb = Wih[(l + 58) * (Dd + 1) + Dd]; }
        }
        WAp[idx] = va;
        WBp[idx] = vb;
    }
}

// ---------------- gemm: GX[m][c] = X[m,:] @ W[:,c] + bias[c] ------------------
// Split-bf16 MFMA, LDS-free: A frags (8 contiguous k/lane) loaded fp32 from X and
// split in-register; B frags read from col-major bf16 hi/lo tables (L2-resident).
// 4 waves (2m x 2n), wave tile 32x64, 24 MFMA / k-step / wave, double-buffered.
__global__ __launch_bounds__(256, 2) void gemm_k(const float* __restrict__ X,
                                                 const u16* __restrict__ Wbh,
                                                 const u16* __restrict__ Wbl,
                                                 const float* __restrict__ bih,
                                                 const float* __restrict__ bhh,
                                                 const float* __restrict__ ba,
                                                 const float* __restrict__ bbp,
                                                 float* __restrict__ GX) {
    const int t    = threadIdx.x;
    const int lane = t & 63;
    const int wid  = t >> 6;
    const int wrow = wid >> 1;            // m half 0..1
    const int wcol = wid & 1;             // n half 0..1
    const int m0   = blockIdx.x * 64 + wrow * 32;
    const int n0   = wcol * 64;
    const int lr   = lane & 15;           // row-in-tile (A) / col-in-tile (B, C/D)
    const int lk   = lane >> 4;           // k-group 0..3 -> k offset lk*8

    const float* xa0 = X + (size_t)(m0 + lr) * Dd + lk * 8;
    const float* xa1 = xa0 + (size_t)16 * Dd;
    const u16*   pbh = Wbh + (size_t)(n0 + lr) * Dd + lk * 8;
    const u16*   pbl = Wbl + (size_t)(n0 + lr) * Dd + lk * 8;

    f32x4 acc[2][4];
#pragma unroll
    for (int nt = 0; nt < 4; nt++) {
        int c = n0 + nt * 16 + lr;
        float bv = (c < 120) ? (bih[c] + bhh[c])
                 : (c == 120) ? ba[0]
                 : (c == 121) ? bbp[0] : 0.f;
        f32x4 v = {bv, bv, bv, bv};
        acc[0][nt] = v;
        acc[1][nt] = v;
    }

#define LOADA(ra, ks) do {                                        \
        ra[0] = *(const float4*)(xa0 + (ks) * 32);                \
        ra[1] = *(const float4*)(xa0 + (ks) * 32 + 4);            \
        ra[2] = *(const float4*)(xa1 + (ks) * 32);                \
        ra[3] = *(const float4*)(xa1 + (ks) * 32 + 4);            \
    } while (0)

#define LOADB(bh, bl, ks) do {                                               \
        _Pragma("unroll")                                                    \
        for (int nt = 0; nt < 4; nt++) {                                     \
            bh[nt] = *(const short8v*)(pbh + (size_t)nt * 16 * Dd + (ks) * 32); \
            bl[nt] = *(const short8v*)(pbl + (size_t)nt * 16 * Dd + (ks) * 32); \
        }                                                                    \
    } while (0)

#define STEP(ra, bh, bl) do {                                     \
        short8v ah0, al0, ah1, al1;                               \
        cvt_split(ra[0], ra[1], ah0, al0);                        \
        cvt_split(ra[2], ra[3], ah1, al1);                        \
        _Pragma("unroll")                                         \
        for (int nt = 0; nt < 4; nt++)                            \
            acc[0][nt] = mm_bf16(ah0, bh[nt], acc[0][nt]);        \
        _Pragma("unroll")                                         \
        for (int nt = 0; nt < 4; nt++)                            \
            acc[1][nt] = mm_bf16(ah1, bh[nt], acc[1][nt]);        \
        _Pragma("unroll")                                         \
        for (int nt = 0; nt < 4; nt++)                            \
            acc[0][nt] = mm_bf16(al0, bh[nt], acc[0][nt]);        \
        _Pragma("unroll")                                         \
        for (int nt = 0; nt < 4; nt++)                            \
            acc[1][nt] = mm_bf16(al1, bh[nt], acc[1][nt]);        \
        _Pragma("unroll")                                         \
        for (int nt = 0; nt < 4; nt++)                            \
            acc[0][nt] = mm_bf16(ah0, bl[nt], acc[0][nt]);        \
        _Pragma("unroll")                                         \
        for (int nt = 0; nt < 4; nt++)                            \
            acc[1][nt] = mm_bf16(ah1, bl[nt], acc[1][nt]);        \
    } while (0)

    float4  ra0[4], ra1[4];
    short8v bh0[4], bl0[4], bh1[4], bl1[4];

    LOADA(ra0, 0);
    LOADB(bh0, bl0, 0);
    int ks = 0;
    for (; ks < KSTEPS - 2; ks += 2) {
        LOADA(ra1, ks + 1);
        LOADB(bh1, bl1, ks + 1);
        STEP(ra0, bh0, bl0);
        LOADA(ra0, ks + 2);
        LOADB(bh0, bl0, ks + 2);
        STEP(ra1, bh1, bl1);
    }
    LOADA(ra1, KSTEPS - 1);
    LOADB(bh1, bl1, KSTEPS - 1);
    STEP(ra0, bh0, bl0);
    STEP(ra1, bh1, bl1);

#undef LOADA
#undef LOADB
#undef STEP

    // C/D layout (m89-verified): col = lane&15, row = (lane>>4)*4 + reg
#pragma unroll
    for (int mt = 0; mt < 2; mt++)
#pragma unroll
        for (int nt = 0; nt < 4; nt++) {
            float* dst = GX + (size_t)(m0 + mt * 16 + lk * 4) * NC + n0 + nt * 16 + lr;
#pragma unroll
            for (int r = 0; r < 4; r++)
                dst[(size_t)r * NC] = acc[mt][nt][r];
        }
}

// pin 16 array elements into live VGPRs at this program point (zero instructions)
#define PIN16(A, B) asm volatile("" \
    : "+v"(A[B+0]), "+v"(A[B+1]), "+v"(A[B+2]),  "+v"(A[B+3]),  "+v"(A[B+4]),  "+v"(A[B+5]),  "+v"(A[B+6]),  "+v"(A[B+7]), \
      "+v"(A[B+8]), "+v"(A[B+9]), "+v"(A[B+10]), "+v"(A[B+11]), "+v"(A[B+12]), "+v"(A[B+13]), "+v"(A[B+14]), "+v"(A[B+15]))

// ---------------- scan: one wave per batch row (UNCHANGED this round) ---------
__global__
__attribute__((amdgpu_flat_work_group_size(64, 64)))
__attribute__((amdgpu_waves_per_eu(1)))
void scan_k(const float* __restrict__ u,
            const float* __restrict__ gx,
            const float* __restrict__ WAp,
            const float* __restrict__ WBp,
            float* __restrict__ out) {
    __shared__ float lus[Tt];
    __shared__ float zbuf[Tt];
    const int b = blockIdx.x;
    const int l = threadIdx.x;

    for (int k = l; k < Tt; k += 64) {
        float uu = u[b * Tt + k];
        uu = fminf(fmaxf(uu, 1e-5f), 1.f - 1e-5f);
        lus[k] = __logf(1.f - uu);
    }
    __syncthreads();

    // per-lane weights: 32 floats each -> VGPRs
    float wA[32], wB[32];
#pragma unroll
    for (int j = 0; j < 8; j++) {
        float4 a4 = ((const float4*)(WAp + l * 32))[j];
        float4 b4 = ((const float4*)(WBp + l * 32))[j];
        wA[4 * j + 0] = a4.x; wA[4 * j + 1] = a4.y; wA[4 * j + 2] = a4.z; wA[4 * j + 3] = a4.w;
        wB[4 * j + 0] = b4.x; wB[4 * j + 1] = b4.y; wB[4 * j + 2] = b4.z; wB[4 * j + 3] = b4.w;
    }

    int cA, cB;
    if (l < 30)       { cA = l;       cB = 30 + l; }
    else if (l == 30) { cA = 120;     cB = 122; }
    else if (l == 31) { cA = 121;     cB = 123; }
    else if (l < 62)  { cA = l + 28;  cB = l + 58; }
    else              { cA = 126;     cB = 127; }
    const float* gxb = gx + (size_t)b * Tt * NC;

    float h[Hh];
#pragma unroll
    for (int k = 0; k < Hh; k++) h[k] = 0.f;
    float cst = 0.f;

    // depth-2 software pipeline on GX rows and lu
    float gA0 = gxb[cA], gB0 = gxb[cB];
    float gA1 = gxb[NC + cA], gB1 = gxb[NC + cB];
    float lu0 = lus[0], lu1 = lus[1];

    const int srcb = ((l & 31) + 32) << 2;   // lanes 0..29 pull from 32..61

    for (int t = 0; t < Tt; t++) {
        // force weight residency in VGPRs every iteration (0 instructions)
        PIN16(wA, 0); PIN16(wA, 16);
        PIN16(wB, 0); PIN16(wB, 16);

        // 4-way split h-dot to cut FMA dependency chain
        float a0 = gA0, a1 = 0.f, a2 = 0.f, a3 = 0.f;
        float b0 = gB0, b1 = 0.f, b2 = 0.f, b3 = 0.f;
#pragma unroll
        for (int k = 0; k < 28; k += 4) {
            a0 = fmaf(wA[k], h[k], a0);         a1 = fmaf(wA[k + 1], h[k + 1], a1);
            a2 = fmaf(wA[k + 2], h[k + 2], a2); a3 = fmaf(wA[k + 3], h[k + 3], a3);
            b0 = fmaf(wB[k], h[k], b0);         b1 = fmaf(wB[k + 1], h[k + 1], b1);
            b2 = fmaf(wB[k + 2], h[k + 2], b2); b3 = fmaf(wB[k + 3], h[k + 3], b3);
        }
        a0 = fmaf(wA[28], h[28], a0); a1 = fmaf(wA[29], h[29], a1);
        b0 = fmaf(wB[28], h[28], b0); b1 = fmaf(wB[29], h[29], b1);
        float accA = (a0 + a2) + (a1 + a3);
        float accB = (b0 + b2) + (b1 + b3);

        // rotate pipeline, prefetch t+2
        gA0 = gA1; gB0 = gB1;
        float lu = lu0; lu0 = lu1;
        if (t + 2 < Tt) {
            gA1 = gxb[(size_t)(t + 2) * NC + cA];
            gB1 = gxb[(size_t)(t + 2) * NC + cB];
            lu1 = lus[t + 2];
        }

        // a, b scalars from lanes 30/31 (pre z-injection)
        const float av = rl_f(accA, 30);
        const float bv = rl_f(accA, 31);
        float a  = fminf(fmaxf(softplus_(av), 1e-6f), 100.f);
        float bk = fminf(fmaxf(softplus_(bv), 1e-6f), 100.f);
        // HardKuma sample: s = (1 - (1-u)^(1/b))^(1/a), divides as rcp-muls
        float p = __expf(lu * rcpf_(bk));
        float inner = 1.f - p;
        float s = (inner <= 0.f) ? 0.f : __expf(__logf(inner) * rcpf_(a));
        float z = fminf(fmaxf(fmaf(1.2f, s, -0.1f), 0.f), 1.f);

        // inject z * Wih[:,D]
        accA = fmaf(z, wA[30], accA);
        accB = fmaf(z, wB[30], accB);

        // transcendentals BEFORE the permute so they overlap its latency
        const float tg = tanhf_fast(accA);     // tanh(g) valid on upper lanes
        const float sA = sigmoidf_(accA);      // sigmoid(i) valid on lower lanes
        const float sB = sigmoidf_(accB);      // sigmoid(f) lower / sigmoid(o) upper
        const float gg_t = __uint_as_float(__builtin_amdgcn_ds_bpermute(srcb, __float_as_uint(tg)));
        const float oo_s = __uint_as_float(__builtin_amdgcn_ds_bpermute(srcb, __float_as_uint(sB)));

        const float cn = fmaf(sB, cst, sA * gg_t);
        const float hn = oo_s * tanhf_fast(cn);
        cst = cn;
#pragma unroll
        for (int k = 0; k < Hh; k++) h[k] = rl_f(hn, k);
        if (l == 0) zbuf[t] = z;
    }
    __syncthreads();
    for (int k = l; k < Tt; k += 64) out[b * Tt + k] = zbuf[k];
}

extern "C" void kernel_launch(void* const* d_in, const int* in_sizes, int n_in,
                              void* d_out, int out_size, void* d_ws, size_t ws_size,
                              hipStream_t stream) {
    const float* x   = (const float*)d_in[0];
    const float* u   = (const float*)d_in[1];
    const float* Wih = (const float*)d_in[2];
    const float* Whh = (const float*)d_in[3];
    const float* bih = (const float*)d_in[4];
    const float* bhh = (const float*)d_in[5];
    const float* Wa  = (const float*)d_in[6];
    const float* ba  = (const float*)d_in[7];
    const float* Wb  = (const float*)d_in[8];
    const float* bbp = (const float*)d_in[9];
    float* out = (float*)d_out;

    // ws layout (bytes):
    char* wsb = (char*)d_ws;
    u16*   Wbh = (u16*)(wsb);                    // 128*1536*2 = 393216
    u16*   Wbl = (u16*)(wsb + 393216);           // 393216  (fits old Wp footprint)
    float* WAp = (float*)(wsb + 786432);         // 64*32*4 = 8192
    float* WBp = (float*)(wsb + 794624);         // 8192
    float* GX  = (float*)(wsb + 802816);         // 32768*128*4 = 16777216

    pack_w<<<dim3(Dd / 256, NC), 256, 0, stream>>>(Wih, Wa, Wb, Wbh, Wbl);
    pack_s<<<1, 256, 0, stream>>>(Wih, Whh, Wa, Wb, WAp, WBp);
    gemm_k<<<Mm / 64, 256, 0, stream>>>(x, Wbh, Wbl, bih, bhh, ba, bbp, GX);
    scan_k<<<Bb, 64, 0, stream>>>(u, GX, WAp, WBp, out);
}

// Round 2
// 754.124 us; speedup vs baseline: 1.0748x; 1.0378x over previous
//
#include <hip/hip_runtime.h>
#include <math.h>

#define Bb 64
#define Tt 512
#define Dd 1536
#define Hh 30
#define NC 128            // packed GX cols: gate layout unchanged
#define Mm (Bb*Tt)        // 32768 rows
#define KSTEPS 48         // 1536 / 32

typedef unsigned short u16;
typedef __attribute__((ext_vector_type(8))) short short8v;  // 8 bf16 = 4 VGPRs
typedef __attribute__((ext_vector_type(4))) float f32x4;
typedef unsigned int uint2v __attribute__((ext_vector_type(2)));

__device__ __forceinline__ float rcpf_(float x) { return __builtin_amdgcn_rcpf(x); }
__device__ __forceinline__ float sigmoidf_(float x) {
    return rcpf_(1.f + __expf(-x));
}
__device__ __forceinline__ float tanhf_fast(float x) {
    float e = __expf(2.f * x);
    return fmaf(-2.f, rcpf_(e + 1.f), 1.f);
}
__device__ __forceinline__ float softplus_(float x) {
    return fmaxf(x, 0.f) + __logf(1.f + __expf(-fabsf(x)));
}
__device__ __forceinline__ float rl_f(float v, int lane) {
    return __uint_as_float(__builtin_amdgcn_readlane(__float_as_uint(v), lane));
}

// v_permlane32_swap_b32: x'[0..31]=x[0..31], x'[32..63]=y[0..31],
//                        y'[0..31]=x[32..63], y'[32..63]=y[32..63]
__device__ __forceinline__ void plswap(float& x, float& y) {
#if __has_builtin(__builtin_amdgcn_permlane32_swap)
    uint2v r = __builtin_amdgcn_permlane32_swap(__float_as_uint(x), __float_as_uint(y), false, false);
    x = __uint_as_float(r.x);
    y = __uint_as_float(r.y);
#else
    asm volatile("v_permlane32_swap_b32 %0, %1" : "+v"(x), "+v"(y));
#endif
}

__device__ __forceinline__ f32x4 mm_bf16(short8v a, short8v b, f32x4 c) {
    return __builtin_amdgcn_mfma_f32_16x16x32_bf16(a, b, c, 0, 0, 0);
}

union U4S8 { unsigned int u[4]; short8v s; };

// exact hi/lo split: x = hi + lo with hi = trunc-bf16(x)
__device__ __forceinline__ void cvt_split(const float4 a, const float4 b,
                                          short8v& hi, short8v& lo) {
    float x[8] = {a.x, a.y, a.z, a.w, b.x, b.y, b.z, b.w};
    U4S8 H, L;
#pragma unroll
    for (int i = 0; i < 4; i++) {
        unsigned int u0 = __float_as_uint(x[2 * i]);
        unsigned int u1 = __float_as_uint(x[2 * i + 1]);
        unsigned int h0 = u0 & 0xffff0000u;
        unsigned int h1 = u1 & 0xffff0000u;
        H.u[i] = (u0 >> 16) | h1;
        float l0 = x[2 * i]     - __uint_as_float(h0);
        float l1 = x[2 * i + 1] - __uint_as_float(h1);
        L.u[i] = (__float_as_uint(l0) >> 16) | (__float_as_uint(l1) & 0xffff0000u);
    }
    hi = H.s;
    lo = L.s;
}

// ---------------- pack 1: W -> bf16 hi/lo, col-major Wb*[c][k] ----------------
__global__ __launch_bounds__(256) void pack_w(const float* __restrict__ Wih,
                                              const float* __restrict__ Wa,
                                              const float* __restrict__ Wb,
                                              u16* __restrict__ Wbh,
                                              u16* __restrict__ Wbl) {
    const int k = blockIdx.x * 256 + threadIdx.x;  // 0..1535
    const int c = blockIdx.y;                      // 0..127
    float v = 0.f;
    if (c < 120)       v = Wih[c * (Dd + 1) + k];
    else if (c == 120) v = Wa[k];
    else if (c == 121) v = Wb[k];
    unsigned int u = __float_as_uint(v);
    unsigned int h = u & 0xffff0000u;
    float lo = v - __uint_as_float(h);
    Wbh[(size_t)c * Dd + k] = (u16)(u >> 16);
    Wbl[(size_t)c * Dd + k] = (u16)(__float_as_uint(lo) >> 16);
}

// ---------------- pack 2: scan weight tables WAp/WBp[64][32] (UNCHANGED) ------
__global__ __launch_bounds__(256) void pack_s(const float* __restrict__ Wih,
                                              const float* __restrict__ Whh,
                                              const float* __restrict__ Wa,
                                              const float* __restrict__ Wb,
                                              float* __restrict__ WAp,
                                              float* __restrict__ WBp) {
    int t = threadIdx.x;
    for (int idx = t; idx < 64 * 32; idx += 256) {
        int l = idx >> 5, k = idx & 31;
        float va = 0.f, vb = 0.f;
        if (k < 30) {
            if (l < 30)                 { va = Whh[l * Hh + k];        vb = Whh[(30 + l) * Hh + k]; }
            else if (l == 30)           { va = Wa[Dd + k]; }
            else if (l == 31)           { va = Wb[Dd + k]; }
            else if (l < 62)            { va = Whh[(l + 28) * Hh + k]; vb = Whh[(l + 58) * Hh + k]; }
        } else if (k == 30) {
            if (l < 30)                 { va = Wih[l * (Dd + 1) + Dd];        vb = Wih[(30 + l) * (Dd + 1) + Dd]; }
            else if (l >= 32 && l < 62) { va = Wih[(l + 28) * (Dd + 1) + Dd]; vb = Wih[(l + 58) * (Dd + 1) + Dd]; }
        }
        WAp[idx] = va;
        WBp[idx] = vb;
    }
}

// ---------------- gemm: GX[m][c] = X[m,:] @ W[:,c] + bias[c] (UNCHANGED) ------
__global__ __launch_bounds__(256, 2) void gemm_k(const float* __restrict__ X,
                                                 const u16* __restrict__ Wbh,
                                                 const u16* __restrict__ Wbl,
                                                 const float* __restrict__ bih,
                                                 const float* __restrict__ bhh,
                                                 const float* __restrict__ ba,
                                                 const float* __restrict__ bbp,
                                                 float* __restrict__ GX) {
    const int t    = threadIdx.x;
    const int lane = t & 63;
    const int wid  = t >> 6;
    const int wrow = wid >> 1;            // m half 0..1
    const int wcol = wid & 1;             // n half 0..1
    const int m0   = blockIdx.x * 64 + wrow * 32;
    const int n0   = wcol * 64;
    const int lr   = lane & 15;           // row-in-tile (A) / col-in-tile (B, C/D)
    const int lk   = lane >> 4;           // k-group 0..3 -> k offset lk*8

    const float* xa0 = X + (size_t)(m0 + lr) * Dd + lk * 8;
    const float* xa1 = xa0 + (size_t)16 * Dd;
    const u16*   pbh = Wbh + (size_t)(n0 + lr) * Dd + lk * 8;
    const u16*   pbl = Wbl + (size_t)(n0 + lr) * Dd + lk * 8;

    f32x4 acc[2][4];
#pragma unroll
    for (int nt = 0; nt < 4; nt++) {
        int c = n0 + nt * 16 + lr;
        float bv = (c < 120) ? (bih[c] + bhh[c])
                 : (c == 120) ? ba[0]
                 : (c == 121) ? bbp[0] : 0.f;
        f32x4 v = {bv, bv, bv, bv};
        acc[0][nt] = v;
        acc[1][nt] = v;
    }

#define LOADA(ra, ks) do {                                        \
        ra[0] = *(const float4*)(xa0 + (ks) * 32);                \
        ra[1] = *(const float4*)(xa0 + (ks) * 32 + 4);            \
        ra[2] = *(const float4*)(xa1 + (ks) * 32);                \
        ra[3] = *(const float4*)(xa1 + (ks) * 32 + 4);            \
    } while (0)

#define LOADB(bh, bl, ks) do {                                               \
        _Pragma("unroll")                                                    \
        for (int nt = 0; nt < 4; nt++) {                                     \
            bh[nt] = *(const short8v*)(pbh + (size_t)nt * 16 * Dd + (ks) * 32); \
            bl[nt] = *(const short8v*)(pbl + (size_t)nt * 16 * Dd + (ks) * 32); \
        }                                                                    \
    } while (0)

#define STEP(ra, bh, bl) do {                                     \
        short8v ah0, al0, ah1, al1;                               \
        cvt_split(ra[0], ra[1], ah0, al0);                        \
        cvt_split(ra[2], ra[3], ah1, al1);                        \
        _Pragma("unroll")                                         \
        for (int nt = 0; nt < 4; nt++)                            \
            acc[0][nt] = mm_bf16(ah0, bh[nt], acc[0][nt]);        \
        _Pragma("unroll")                                         \
        for (int nt = 0; nt < 4; nt++)                            \
            acc[1][nt] = mm_bf16(ah1, bh[nt], acc[1][nt]);        \
        _Pragma("unroll")                                         \
        for (int nt = 0; nt < 4; nt++)                            \
            acc[0][nt] = mm_bf16(al0, bh[nt], acc[0][nt]);        \
        _Pragma("unroll")                                         \
        for (int nt = 0; nt < 4; nt++)                            \
            acc[1][nt] = mm_bf16(al1, bh[nt], acc[1][nt]);        \
        _Pragma("unroll")                                         \
        for (int nt = 0; nt < 4; nt++)                            \
            acc[0][nt] = mm_bf16(ah0, bl[nt], acc[0][nt]);        \
        _Pragma("unroll")                                         \
        for (int nt = 0; nt < 4; nt++)                            \
            acc[1][nt] = mm_bf16(ah1, bl[nt], acc[1][nt]);        \
    } while (0)

    float4  ra0[4], ra1[4];
    short8v bh0[4], bl0[4], bh1[4], bl1[4];

    LOADA(ra0, 0);
    LOADB(bh0, bl0, 0);
    int ks = 0;
    for (; ks < KSTEPS - 2; ks += 2) {
        LOADA(ra1, ks + 1);
        LOADB(bh1, bl1, ks + 1);
        STEP(ra0, bh0, bl0);
        LOADA(ra0, ks + 2);
        LOADB(bh0, bl0, ks + 2);
        STEP(ra1, bh1, bl1);
    }
    LOADA(ra1, KSTEPS - 1);
    LOADB(bh1, bl1, KSTEPS - 1);
    STEP(ra0, bh0, bl0);
    STEP(ra1, bh1, bl1);

#undef LOADA
#undef LOADB
#undef STEP

    // C/D layout (m89-verified): col = lane&15, row = (lane>>4)*4 + reg
#pragma unroll
    for (int mt = 0; mt < 2; mt++)
#pragma unroll
        for (int nt = 0; nt < 4; nt++) {
            float* dst = GX + (size_t)(m0 + mt * 16 + lk * 4) * NC + n0 + nt * 16 + lr;
#pragma unroll
            for (int r = 0; r < 4; r++)
                dst[(size_t)r * NC] = acc[mt][nt][r];
        }
}

// pin 16 array elements into live VGPRs at this program point (zero instructions)
#define PIN16(A, B) asm volatile("" \
    : "+v"(A[B+0]), "+v"(A[B+1]), "+v"(A[B+2]),  "+v"(A[B+3]),  "+v"(A[B+4]),  "+v"(A[B+5]),  "+v"(A[B+6]),  "+v"(A[B+7]), \
      "+v"(A[B+8]), "+v"(A[B+9]), "+v"(A[B+10]), "+v"(A[B+11]), "+v"(A[B+12]), "+v"(A[B+13]), "+v"(A[B+14]), "+v"(A[B+15]))

// ---------------- scan: one wave per batch row ----------------
// v2: (1) dedicated per-lane z-dot (lanes<32: a-col, lanes>=32: b-col) so the
//     ~110-cycle transcendental z-chain overlaps the 60-FMA gate dot instead of
//     serializing after it; (2) v_permlane32_swap_b32 replaces ds_bpermute
//     (~60-cycle LDS latency -> ~5-cycle VALU) and the readlane(a/b) extraction.
//     All reordered arithmetic is bitwise-identical to v1.
__global__
__attribute__((amdgpu_flat_work_group_size(64, 64)))
__attribute__((amdgpu_waves_per_eu(1)))
void scan_k(const float* __restrict__ u,
            const float* __restrict__ gx,
            const float* __restrict__ WAp,
            const float* __restrict__ WBp,
            float* __restrict__ out) {
    __shared__ float lus[Tt];
    __shared__ float zbuf[Tt];
    const int b = blockIdx.x;
    const int l = threadIdx.x;

    for (int k = l; k < Tt; k += 64) {
        float uu = u[b * Tt + k];
        uu = fminf(fmaxf(uu, 1e-5f), 1.f - 1e-5f);
        lus[k] = __logf(1.f - uu);
    }
    __syncthreads();

    // per-lane weights: gate rows (wA, wB) + z-dot row (wZ = WAp row 30 or 31)
    float wA[32], wB[32], wZ[32];
    const float* wzp = WAp + (l < 32 ? 30 : 31) * 32;
#pragma unroll
    for (int j = 0; j < 8; j++) {
        float4 a4 = ((const float4*)(WAp + l * 32))[j];
        float4 b4 = ((const float4*)(WBp + l * 32))[j];
        float4 z4 = ((const float4*)wzp)[j];
        wA[4 * j + 0] = a4.x; wA[4 * j + 1] = a4.y; wA[4 * j + 2] = a4.z; wA[4 * j + 3] = a4.w;
        wB[4 * j + 0] = b4.x; wB[4 * j + 1] = b4.y; wB[4 * j + 2] = b4.z; wB[4 * j + 3] = b4.w;
        wZ[4 * j + 0] = z4.x; wZ[4 * j + 1] = z4.y; wZ[4 * j + 2] = z4.z; wZ[4 * j + 3] = z4.w;
    }

    int cA, cB;
    if (l < 30)       { cA = l;       cB = 30 + l; }
    else if (l == 30) { cA = 120;     cB = 122; }
    else if (l == 31) { cA = 121;     cB = 123; }
    else if (l < 62)  { cA = l + 28;  cB = l + 58; }
    else              { cA = 126;     cB = 127; }
    const int cZ = (l < 32) ? 120 : 121;
    const float* gxb = gx + (size_t)b * Tt * NC;

    float h[Hh];
#pragma unroll
    for (int k = 0; k < Hh; k++) h[k] = 0.f;
    float cst = 0.f;

    // depth-2 software pipeline on GX rows and lu
    float gA0 = gxb[cA], gB0 = gxb[cB], gZ0 = gxb[cZ];
    float gA1 = gxb[NC + cA], gB1 = gxb[NC + cB], gZ1 = gxb[NC + cZ];
    float lu0 = lus[0], lu1 = lus[1];

    for (int t = 0; t < Tt; t++) {
        // force weight residency in VGPRs every iteration (0 instructions)
        PIN16(wA, 0); PIN16(wA, 16);
        PIN16(wB, 0); PIN16(wB, 16);
        PIN16(wZ, 0); PIN16(wZ, 16);

        // ---- z-dot: lanes<32 compute the a-column, lanes>=32 the b-column ----
        // (same 4-way split order as the old lane-30/31 path -> bitwise identical)
        float z0 = gZ0, z1 = 0.f, z2 = 0.f, z3 = 0.f;
#pragma unroll
        for (int k = 0; k < 28; k += 4) {
            z0 = fmaf(wZ[k], h[k], z0);         z1 = fmaf(wZ[k + 1], h[k + 1], z1);
            z2 = fmaf(wZ[k + 2], h[k + 2], z2); z3 = fmaf(wZ[k + 3], h[k + 3], z3);
        }
        z0 = fmaf(wZ[28], h[28], z0); z1 = fmaf(wZ[29], h[29], z1);
        float zacc = (z0 + z2) + (z1 + z3);
        float sp = softplus_(zacc);
        float spA = sp, spB = sp;
        plswap(spA, spB);                 // spA = sp(a) all lanes, spB = sp(b) all lanes
        float a  = fminf(fmaxf(spA, 1e-6f), 100.f);
        float bk = fminf(fmaxf(spB, 1e-6f), 100.f);

        float lu = lu0;

        // ---- main gate dot (independent of z-chain; scheduler interleaves) ----
        float a0 = gA0, a1 = 0.f, a2 = 0.f, a3 = 0.f;
        float b0 = gB0, b1 = 0.f, b2 = 0.f, b3 = 0.f;
#pragma unroll
        for (int k = 0; k < 28; k += 4) {
            a0 = fmaf(wA[k], h[k], a0);         a1 = fmaf(wA[k + 1], h[k + 1], a1);
            a2 = fmaf(wA[k + 2], h[k + 2], a2); a3 = fmaf(wA[k + 3], h[k + 3], a3);
            b0 = fmaf(wB[k], h[k], b0);         b1 = fmaf(wB[k + 1], h[k + 1], b1);
            b2 = fmaf(wB[k + 2], h[k + 2], b2); b3 = fmaf(wB[k + 3], h[k + 3], b3);
        }
        a0 = fmaf(wA[28], h[28], a0); a1 = fmaf(wA[29], h[29], a1);
        b0 = fmaf(wB[28], h[28], b0); b1 = fmaf(wB[29], h[29], b1);
        float accA = (a0 + a2) + (a1 + a3);
        float accB = (b0 + b2) + (b1 + b3);

        // rotate pipeline, prefetch t+2
        gA0 = gA1; gB0 = gB1; gZ0 = gZ1;
        lu0 = lu1;
        if (t + 2 < Tt) {
            gA1 = gxb[(size_t)(t + 2) * NC + cA];
            gB1 = gxb[(size_t)(t + 2) * NC + cB];
            gZ1 = gxb[(size_t)(t + 2) * NC + cZ];
            lu1 = lus[t + 2];
        }

        // ---- HardKuma sample (valid on every lane now) ----
        float p = __expf(lu * rcpf_(bk));
        float inner = 1.f - p;
        float s = (inner <= 0.f) ? 0.f : __expf(__logf(inner) * rcpf_(a));
        float z = fminf(fmaxf(fmaf(1.2f, s, -0.1f), 0.f), 1.f);

        // inject z * Wih[:,D]
        accA = fmaf(z, wA[30], accA);
        accB = fmaf(z, wB[30], accB);

        // transcendentals, then VALU half-swap (replaces ds_bpermute)
        float tg = tanhf_fast(accA);       // tanh(g) valid on upper lanes
        const float sA = sigmoidf_(accA);  // sigmoid(i) valid on lower lanes
        float sB = sigmoidf_(accB);        // sigmoid(f) lower / sigmoid(o) upper
        float tgx = tg, gg_t = tg;
        plswap(tgx, gg_t);                 // gg_t: lower lanes <- upper tanh(g); upper keep own
        float sBx = sB, oo_s = sB;
        plswap(sBx, oo_s);                 // oo_s: lower lanes <- upper sigmoid(o)

        const float cn = fmaf(sB, cst, sA * gg_t);
        const float hn = oo_s * tanhf_fast(cn);
        cst = cn;
#pragma unroll
        for (int k = 0; k < Hh; k++) h[k] = rl_f(hn, k);
        if (l == 0) zbuf[t] = z;
    }
    __syncthreads();
    for (int k = l; k < Tt; k += 64) out[b * Tt + k] = zbuf[k];
}

extern "C" void kernel_launch(void* const* d_in, const int* in_sizes, int n_in,
                              void* d_out, int out_size, void* d_ws, size_t ws_size,
                              hipStream_t stream) {
    const float* x   = (const float*)d_in[0];
    const float* u   = (const float*)d_in[1];
    const float* Wih = (const float*)d_in[2];
    const float* Whh = (const float*)d_in[3];
    const float* bih = (const float*)d_in[4];
    const float* bhh = (const float*)d_in[5];
    const float* Wa  = (const float*)d_in[6];
    const float* ba  = (const float*)d_in[7];
    const float* Wb  = (const float*)d_in[8];
    const float* bbp = (const float*)d_in[9];
    float* out = (float*)d_out;

    // ws layout (bytes):
    char* wsb = (char*)d_ws;
    u16*   Wbh = (u16*)(wsb);                    // 128*1536*2 = 393216
    u16*   Wbl = (u16*)(wsb + 393216);           // 393216
    float* WAp = (float*)(wsb + 786432);         // 64*32*4 = 8192
    float* WBp = (float*)(wsb + 794624);         // 8192
    float* GX  = (float*)(wsb + 802816);         // 32768*128*4 = 16777216

    pack_w<<<dim3(Dd / 256, NC), 256, 0, stream>>>(Wih, Wa, Wb, Wbh, Wbl);
    pack_s<<<1, 256, 0, stream>>>(Wih, Whh, Wa, Wb, WAp, WBp);
    gemm_k<<<Mm / 64, 256, 0, stream>>>(x, Wbh, Wbl, bih, bhh, ba, bbp, GX);
    scan_k<<<Bb, 64, 0, stream>>>(u, GX, WAp, WBp, out);
}

// Round 4
// 662.117 us; speedup vs baseline: 1.2241x; 1.1390x over previous
//
#include <hip/hip_runtime.h>
#include <math.h>

#define Bb 64
#define Tt 512
#define Dd 1536
#define Hh 30
#define NC 128            // packed GX cols: gate layout unchanged
#define Mm (Bb*Tt)        // 32768 rows
#define KSTEPS 48         // 1536 / 32

typedef unsigned short u16;
typedef __attribute__((ext_vector_type(8))) short short8v;  // 8 bf16 = 4 VGPRs
typedef __attribute__((ext_vector_type(4))) float f32x4;

__device__ __forceinline__ float rcpf_(float x) { return __builtin_amdgcn_rcpf(x); }
__device__ __forceinline__ float sigmoidf_(float x) {
    return rcpf_(1.f + __expf(-x));
}
__device__ __forceinline__ float tanhf_fast(float x) {
    float e = __expf(2.f * x);
    return fmaf(-2.f, rcpf_(e + 1.f), 1.f);
}
__device__ __forceinline__ float softplus_(float x) {
    return fmaxf(x, 0.f) + __logf(1.f + __expf(-fabsf(x)));
}
__device__ __forceinline__ float rl_f(float v, int lane) {
    return __uint_as_float(__builtin_amdgcn_readlane(__float_as_uint(v), lane));
}

__device__ __forceinline__ f32x4 mm_bf16(short8v a, short8v b, f32x4 c) {
    return __builtin_amdgcn_mfma_f32_16x16x32_bf16(a, b, c, 0, 0, 0);
}

union U4S8 { unsigned int u[4]; short8v s; };

// exact hi/lo split: x = hi + lo with hi = trunc-bf16(x)
__device__ __forceinline__ void cvt_split(const float4 a, const float4 b,
                                          short8v& hi, short8v& lo) {
    float x[8] = {a.x, a.y, a.z, a.w, b.x, b.y, b.z, b.w};
    U4S8 H, L;
#pragma unroll
    for (int i = 0; i < 4; i++) {
        unsigned int u0 = __float_as_uint(x[2 * i]);
        unsigned int u1 = __float_as_uint(x[2 * i + 1]);
        unsigned int h0 = u0 & 0xffff0000u;
        unsigned int h1 = u1 & 0xffff0000u;
        H.u[i] = (u0 >> 16) | h1;
        float l0 = x[2 * i]     - __uint_as_float(h0);
        float l1 = x[2 * i + 1] - __uint_as_float(h1);
        L.u[i] = (__float_as_uint(l0) >> 16) | (__float_as_uint(l1) & 0xffff0000u);
    }
    hi = H.s;
    lo = L.s;
}

// ---------------- pack 1: W -> bf16 hi/lo, col-major Wb*[c][k] ----------------
__global__ __launch_bounds__(256) void pack_w(const float* __restrict__ Wih,
                                              const float* __restrict__ Wa,
                                              const float* __restrict__ Wb,
                                              u16* __restrict__ Wbh,
                                              u16* __restrict__ Wbl) {
    const int k = blockIdx.x * 256 + threadIdx.x;  // 0..1535
    const int c = blockIdx.y;                      // 0..127
    float v = 0.f;
    if (c < 120)       v = Wih[c * (Dd + 1) + k];
    else if (c == 120) v = Wa[k];
    else if (c == 121) v = Wb[k];
    unsigned int u = __float_as_uint(v);
    unsigned int h = u & 0xffff0000u;
    float lo = v - __uint_as_float(h);
    Wbh[(size_t)c * Dd + k] = (u16)(u >> 16);
    Wbl[(size_t)c * Dd + k] = (u16)(__float_as_uint(lo) >> 16);
}

// ---------------- pack 2: scan weight table WS2[4][64][32] --------------------
// wave w, lane<32: gate g=lane>>3, k=8w+(lane&7), col c=g*30+k:
//   WS2[j<30] = Whh[c][j], WS2[30] = inject weight Wih[c][Dd], WS2[31] = 0.
// lane 32: Wa[Dd+0..29] (ax row), lane 33: Wb[Dd+0..29] (bx row). Others 0.
__global__ __launch_bounds__(256) void pack_s2(const float* __restrict__ Wih,
                                               const float* __restrict__ Whh,
                                               const float* __restrict__ Wa,
                                               const float* __restrict__ Wb,
                                               float* __restrict__ WS2) {
    const int tid = threadIdx.x;      // 0..255
    const int w = tid >> 6, lane = tid & 63;
    float v[32];
#pragma unroll
    for (int j = 0; j < 32; j++) v[j] = 0.f;
    if (lane < 32) {
        int g = lane >> 3, k = 8 * w + (lane & 7);
        if (k < 30) {
            int cc = g * 30 + k;
            for (int j = 0; j < 30; j++) v[j] = Whh[cc * Hh + j];
            v[30] = Wih[cc * (Dd + 1) + Dd];
        }
    } else if (lane == 32) {
        for (int j = 0; j < 30; j++) v[j] = Wa[Dd + j];
    } else if (lane == 33) {
        for (int j = 0; j < 30; j++) v[j] = Wb[Dd + j];
    }
    float* dst = WS2 + (size_t)tid * 32;
    for (int j = 0; j < 32; j++) dst[j] = v[j];
}

// ---------------- gemm: GX[m][c] = X[m,:] @ W[:,c] + bias[c] (UNCHANGED) ------
__global__ __launch_bounds__(256, 2) void gemm_k(const float* __restrict__ X,
                                                 const u16* __restrict__ Wbh,
                                                 const u16* __restrict__ Wbl,
                                                 const float* __restrict__ bih,
                                                 const float* __restrict__ bhh,
                                                 const float* __restrict__ ba,
                                                 const float* __restrict__ bbp,
                                                 float* __restrict__ GX) {
    const int t    = threadIdx.x;
    const int lane = t & 63;
    const int wid  = t >> 6;
    const int wrow = wid >> 1;            // m half 0..1
    const int wcol = wid & 1;             // n half 0..1
    const int m0   = blockIdx.x * 64 + wrow * 32;
    const int n0   = wcol * 64;
    const int lr   = lane & 15;           // row-in-tile (A) / col-in-tile (B, C/D)
    const int lk   = lane >> 4;           // k-group 0..3 -> k offset lk*8

    const float* xa0 = X + (size_t)(m0 + lr) * Dd + lk * 8;
    const float* xa1 = xa0 + (size_t)16 * Dd;
    const u16*   pbh = Wbh + (size_t)(n0 + lr) * Dd + lk * 8;
    const u16*   pbl = Wbl + (size_t)(n0 + lr) * Dd + lk * 8;

    f32x4 acc[2][4];
#pragma unroll
    for (int nt = 0; nt < 4; nt++) {
        int c = n0 + nt * 16 + lr;
        float bv = (c < 120) ? (bih[c] + bhh[c])
                 : (c == 120) ? ba[0]
                 : (c == 121) ? bbp[0] : 0.f;
        f32x4 v = {bv, bv, bv, bv};
        acc[0][nt] = v;
        acc[1][nt] = v;
    }

#define LOADA(ra, ks) do {                                        \
        ra[0] = *(const float4*)(xa0 + (ks) * 32);                \
        ra[1] = *(const float4*)(xa0 + (ks) * 32 + 4);            \
        ra[2] = *(const float4*)(xa1 + (ks) * 32);                \
        ra[3] = *(const float4*)(xa1 + (ks) * 32 + 4);            \
    } while (0)

#define LOADB(bh, bl, ks) do {                                               \
        _Pragma("unroll")                                                    \
        for (int nt = 0; nt < 4; nt++) {                                     \
            bh[nt] = *(const short8v*)(pbh + (size_t)nt * 16 * Dd + (ks) * 32); \
            bl[nt] = *(const short8v*)(pbl + (size_t)nt * 16 * Dd + (ks) * 32); \
        }                                                                    \
    } while (0)

#define STEP(ra, bh, bl) do {                                     \
        short8v ah0, al0, ah1, al1;                               \
        cvt_split(ra[0], ra[1], ah0, al0);                        \
        cvt_split(ra[2], ra[3], ah1, al1);                        \
        _Pragma("unroll")                                         \
        for (int nt = 0; nt < 4; nt++)                            \
            acc[0][nt] = mm_bf16(ah0, bh[nt], acc[0][nt]);        \
        _Pragma("unroll")                                         \
        for (int nt = 0; nt < 4; nt++)                            \
            acc[1][nt] = mm_bf16(ah1, bh[nt], acc[1][nt]);        \
        _Pragma("unroll")                                         \
        for (int nt = 0; nt < 4; nt++)                            \
            acc[0][nt] = mm_bf16(al0, bh[nt], acc[0][nt]);        \
        _Pragma("unroll")                                         \
        for (int nt = 0; nt < 4; nt++)                            \
            acc[1][nt] = mm_bf16(al1, bh[nt], acc[1][nt]);        \
        _Pragma("unroll")                                         \
        for (int nt = 0; nt < 4; nt++)                            \
            acc[0][nt] = mm_bf16(ah0, bl[nt], acc[0][nt]);        \
        _Pragma("unroll")                                         \
        for (int nt = 0; nt < 4; nt++)                            \
            acc[1][nt] = mm_bf16(ah1, bl[nt], acc[1][nt]);        \
    } while (0)

    float4  ra0[4], ra1[4];
    short8v bh0[4], bl0[4], bh1[4], bl1[4];

    LOADA(ra0, 0);
    LOADB(bh0, bl0, 0);
    int ks = 0;
    for (; ks < KSTEPS - 2; ks += 2) {
        LOADA(ra1, ks + 1);
        LOADB(bh1, bl1, ks + 1);
        STEP(ra0, bh0, bl0);
        LOADA(ra0, ks + 2);
        LOADB(bh0, bl0, ks + 2);
        STEP(ra1, bh1, bl1);
    }
    LOADA(ra1, KSTEPS - 1);
    LOADB(bh1, bl1, KSTEPS - 1);
    STEP(ra0, bh0, bl0);
    STEP(ra1, bh1, bl1);

#undef LOADA
#undef LOADB
#undef STEP

    // C/D layout (m89-verified): col = lane&15, row = (lane>>4)*4 + reg
#pragma unroll
    for (int mt = 0; mt < 2; mt++)
#pragma unroll
        for (int nt = 0; nt < 4; nt++) {
            float* dst = GX + (size_t)(m0 + mt * 16 + lk * 4) * NC + n0 + nt * 16 + lr;
#pragma unroll
            for (int r = 0; r < 4; r++)
                dst[(size_t)r * NC] = acc[mt][nt][r];
        }
}

// pin 16 array elements into live VGPRs at this program point (zero instructions)
#define PIN16(A, B) asm volatile("" \
    : "+v"(A[B+0]), "+v"(A[B+1]), "+v"(A[B+2]),  "+v"(A[B+3]),  "+v"(A[B+4]),  "+v"(A[B+5]),  "+v"(A[B+6]),  "+v"(A[B+7]), \
      "+v"(A[B+8]), "+v"(A[B+9]), "+v"(A[B+10]), "+v"(A[B+11]), "+v"(A[B+12]), "+v"(A[B+13]), "+v"(A[B+14]), "+v"(A[B+15]))

// ---------------- scan v3: 4 cooperative waves per batch ----------------------
// Wave w owns h-indices k in [8w, 8w+8). Lane = gate*8 + dk (gate: 0=i,1=f,2=g,
// 3=o); lanes 32/33 redundantly compute ax/bx dots on EVERY wave so the uniform
// z-chain needs no cross-wave traffic. Gates for index k sit on lanes dk, dk+8,
// dk+16, dk+24 -> gathered by 3 ds_swizzle (lane^8/^16/^24). cn/cst/hn live on
// i-lanes. One barrier per step; h double-buffered in LDS, read back as 8
// broadcast ds_read_b128. All arithmetic bitwise-identical to v2.
__global__
__attribute__((amdgpu_flat_work_group_size(256, 256)))
__attribute__((amdgpu_waves_per_eu(1)))
void scan_k(const float* __restrict__ u,
            const float* __restrict__ gx,
            const float* __restrict__ WS2,
            float* __restrict__ out) {
    __shared__ float lus[Tt];
    __shared__ float zbuf[Tt];
    __shared__ float hb[2][32];
    const int b   = blockIdx.x;
    const int tid = threadIdx.x;
    const int w   = tid >> 6;
    const int lane = tid & 63;

    for (int k = tid; k < Tt; k += 256) {
        float uu = u[b * Tt + k];
        uu = fminf(fmaxf(uu, 1e-5f), 1.f - 1e-5f);
        lus[k] = __logf(1.f - uu);
    }
    if (tid < 64) ((float*)hb)[tid] = 0.f;
    __syncthreads();

    // per-lane weights: 32 floats -> VGPRs
    float wv[32];
    {
        const float* wp = WS2 + (size_t)((w << 6) + lane) * 32;
#pragma unroll
        for (int j = 0; j < 8; j++) {
            float4 v4 = ((const float4*)wp)[j];
            wv[4 * j + 0] = v4.x; wv[4 * j + 1] = v4.y;
            wv[4 * j + 2] = v4.z; wv[4 * j + 3] = v4.w;
        }
    }

    // gx column for this lane
    int c;
    if (lane < 32) { int g = lane >> 3, k = 8 * w + (lane & 7); c = (k < 30) ? g * 30 + k : 124; }
    else if (lane == 32) c = 120;
    else if (lane == 33) c = 121;
    else c = 124;
    const float* gxb = gx + (size_t)b * Tt * NC + c;

    const bool isg = (lane < 32) && ((lane >> 3) == 2);   // tanh lanes (g-gate)

    float h[32];
#pragma unroll
    for (int k = 0; k < 32; k++) h[k] = 0.f;
    float cst = 0.f;

    // depth-2 prefetch pipeline on GX and lu
    float g0 = gxb[0];
    float g1 = gxb[NC];
    float lu0 = lus[0], lu1 = lus[1];

    for (int t = 0; t < Tt; t++) {
        PIN16(wv, 0); PIN16(wv, 16);

        // per-lane gate dot, same 4-way split order as v2 (bitwise identical)
        float a0 = g0, a1 = 0.f, a2 = 0.f, a3 = 0.f;
#pragma unroll
        for (int k = 0; k < 28; k += 4) {
            a0 = fmaf(wv[k], h[k], a0);         a1 = fmaf(wv[k + 1], h[k + 1], a1);
            a2 = fmaf(wv[k + 2], h[k + 2], a2); a3 = fmaf(wv[k + 3], h[k + 3], a3);
        }
        a0 = fmaf(wv[28], h[28], a0); a1 = fmaf(wv[29], h[29], a1);
        float acc = (a0 + a2) + (a1 + a3);

        // uniform z-chain from the redundant ax/bx dots (lanes 32/33)
        const float av = rl_f(acc, 32);
        const float bv = rl_f(acc, 33);
        float a  = fminf(fmaxf(softplus_(av), 1e-6f), 100.f);
        float bk = fminf(fmaxf(softplus_(bv), 1e-6f), 100.f);
        float lu = lu0;
        float p = __expf(lu * rcpf_(bk));
        float inner = 1.f - p;
        float s = (inner <= 0.f) ? 0.f : __expf(__logf(inner) * rcpf_(a));
        float z = fminf(fmaxf(fmaf(1.2f, s, -0.1f), 0.f), 1.f);

        // rotate prefetch, fetch t+2
        g0 = g1; lu0 = lu1;
        if (t + 2 < Tt) {
            g1 = gxb[(size_t)(t + 2) * NC];
            lu1 = lus[t + 2];
        }

        // inject z * Wih[:,D]
        acc = fmaf(z, wv[30], acc);

        // nonlinearity: tanh on g-lanes, sigmoid elsewhere
        float tt = tanhf_fast(acc);
        float ss = sigmoidf_(acc);
        float val = isg ? tt : ss;

        // gather f, g, o onto i-lanes (lane^8, ^16, ^24 within 32-lane group)
        float vf = __uint_as_float(__builtin_amdgcn_ds_swizzle(__float_as_uint(val), 0x201F));
        float vg = __uint_as_float(__builtin_amdgcn_ds_swizzle(__float_as_uint(val), 0x401F));
        float vo = __uint_as_float(__builtin_amdgcn_ds_swizzle(__float_as_uint(val), 0x601F));

        // LSTM combine on i-lanes: cn = sig(f)*c + sig(i)*tanh(g)
        float cn = fmaf(vf, cst, val * vg);
        float hn = vo * tanhf_fast(cn);
        cst = cn;

        float* hbw = &hb[(t + 1) & 1][0];
        if (lane < 8) hbw[8 * w + lane] = hn;
        if (tid == 0) zbuf[t] = z;
        __syncthreads();

        // broadcast-read next h state (uniform addresses -> no conflicts)
#pragma unroll
        for (int j = 0; j < 8; j++) {
            float4 h4 = ((const float4*)hbw)[j];
            h[4 * j + 0] = h4.x; h[4 * j + 1] = h4.y;
            h[4 * j + 2] = h4.z; h[4 * j + 3] = h4.w;
        }
    }
    __syncthreads();
    for (int k = tid; k < Tt; k += 256) out[b * Tt + k] = zbuf[k];
}

extern "C" void kernel_launch(void* const* d_in, const int* in_sizes, int n_in,
                              void* d_out, int out_size, void* d_ws, size_t ws_size,
                              hipStream_t stream) {
    const float* x   = (const float*)d_in[0];
    const float* u   = (const float*)d_in[1];
    const float* Wih = (const float*)d_in[2];
    const float* Whh = (const float*)d_in[3];
    const float* bih = (const float*)d_in[4];
    const float* bhh = (const float*)d_in[5];
    const float* Wa  = (const float*)d_in[6];
    const float* ba  = (const float*)d_in[7];
    const float* Wb  = (const float*)d_in[8];
    const float* bbp = (const float*)d_in[9];
    float* out = (float*)d_out;

    // ws layout (bytes):
    char* wsb = (char*)d_ws;
    u16*   Wbh = (u16*)(wsb);                    // 128*1536*2 = 393216
    u16*   Wbl = (u16*)(wsb + 393216);           // 393216
    float* WS2 = (float*)(wsb + 786432);         // 4*64*32*4 = 32768
    float* GX  = (float*)(wsb + 819200);         // 32768*128*4 = 16777216

    pack_w<<<dim3(Dd / 256, NC), 256, 0, stream>>>(Wih, Wa, Wb, Wbh, Wbl);
    pack_s2<<<1, 256, 0, stream>>>(Wih, Whh, Wa, Wb, WS2);
    gemm_k<<<Mm / 64, 256, 0, stream>>>(x, Wbh, Wbl, bih, bhh, ba, bbp, GX);
    scan_k<<<Bb, 256, 0, stream>>>(u, GX, WS2, out);
}